// Round 7
// baseline (32.843 us; speedup 1.0000x reference)
//
#include <hip/hip_runtime.h>
#include <stdint.h>

constexpr int BATCH = 16384;
constexpr int A     = 50;
constexpr int NN    = 51;   // A + 1
constexpr int MAXR  = 16;
constexpr int EPW   = 4;    // elements per wave (16 lanes per element)
constexpr int WPB   = 4;    // waves per block

// Fused kernel, 4 elements/wave: phase A builds trees (16-lane element groups,
// role-split, prefetch-pipelined), phase B reconstructs rings with the 4
// elements' mask-doubling chains interleaved. No __syncthreads anywhere.
// 4096 waves -> 4 waves/SIMD for latency hiding.
__global__ __launch_bounds__(WPB * 64, 4)
void fused_kernel(const int* __restrict__ edge, int* __restrict__ out)
{
    const int lane  = threadIdx.x & 63;
    const int wid   = threadIdx.x >> 6;
    const int gbase = (blockIdx.x * WPB + wid) * EPW;  // this wave's first element

    __shared__ uint32_t eds[WPB][EPW][NN];   // packed me[e][n+1][0..3]
    __shared__ uint8_t  tre[WPB][EPW][52];   // Tree bytes; slot 51 = trash
    __shared__ uint8_t  rg [WPB][EPW][104];  // ring_idx pairs; offset 102 = trash

    {   // zero tre + rg (wave-private slices)
        const uint4 z = make_uint4(0, 0, 0, 0);
        uint4* t16 = (uint4*)&tre[wid][0][0];           // 4*52/16 = 13
        if (lane < 13) t16[lane] = z;
        uint4* r16 = (uint4*)&rg[wid][0][0];            // 4*104/16 = 26
        if (lane < 26) r16[lane] = z;
    }
    {   // stage + pack this wave's edges: 4 elements x 50 int4, coalesced
        const int4* e4 = (const int4*)edge + (size_t)gbase * A;
        #pragma unroll
        for (int k = 0; k < 4; ++k) {
            const int gi = k * 64 + lane;
            if (gi < EPW * A) {
                const int4 v = e4[gi];
                const int el = gi / A, n = gi - A * el;
                eds[wid][el][n] = (uint32_t)(v.x + 1) | ((uint32_t)(v.y + 1) << 8)
                                | ((uint32_t)(v.z + 1) << 16) | ((uint32_t)(v.w + 1) << 24);
            }
        }
    }
    // (same-wave LDS RAW: hardware lgkmcnt ordering, no barrier needed)

    // ---------------- phase A: tree construction ----------------
    const int  e    = lane >> 4;   // element within wave
    const int  d16  = lane & 15;
    const int  d    = d16 & 3;     // edge index this lane mirrors
    const bool hi   = (d16 >> 2) == 1;  // role 1: does the rg store
    const bool st8  = d16 < 8;     // roles 0,1 store; roles 2,3 idle-mirror

    uint64_t L = (((uint64_t)1 << NN) - 1) & ~(uint64_t)3;  // lnf: 0,1 found
    uint64_t V = (((uint64_t)1 << NN) - 1) & ~(uint64_t)1;  // nnv: 0 visited
    uint64_t M = 2;                // found & not visited = {1}
    int visiting = 1, nr = 0;
    uint32_t w = eds[wid][e][0];   // prefetched row of node 1

    #pragma unroll 1
    for (int it = 0; it < A; ++it) {
        const int n0 = w & 0xff, n1 = (w >> 8) & 0xff, n2 = (w >> 16) & 0xff, n3 = w >> 24;
        const uint64_t bu = ((uint64_t)1 << n0) | ((uint64_t)1 << n1)
                          | ((uint64_t)1 << n2) | ((uint64_t)1 << n3);
        const int myn = (w >> (8 * d)) & 0xff;
        const uint64_t bm = (uint64_t)1 << myn;
        // --- next-visit precompute + prefetch (overlaps bookkeeping) ---
        const uint64_t visbit = (uint64_t)1 << visiting;
        const uint64_t Mn = (M | (V & bu)) & ~visbit;   // next found&!visited set
        const bool dn = (Mn == 0);
        const uint64_t Msafe = dn ? (uint64_t)2 : Mn;
        const int nv = (int)__builtin_ctzll(Msafe);     // next visiting (dummy 1 if done)
        const uint32_t wn = eds[wid][e][nv - 1];        // prefetch next edge row
        // --- bookkeeping with OLD L,V ---
        const bool dup = ((d > 0) & (myn == n0)) | ((d > 1) & (myn == n1)) | ((d > 2) & (myn == n2));
        const bool fa  = ((L & bm) == 0) | dup;         // found at my edge's turn
        const bool cf  = fa & ((V & bm) != 0) & (myn != 0);   // cycle edge
        const bool cb  = cf & (d16 < 4);                // ballot only role-0 lanes
        const uint64_t Bc = __ballot(cb);
        const uint32_t qb = (uint32_t)(Bc >> (lane & 48)) & 0xfu;  // my element's bits
        const int slot = nr + __builtin_popcount(qb & ((1u << d) - 1));
        nr += __builtin_popcount(qb);
        if (st8) {
            // role 0: Tree set-once; role 1: ring slot push (trash-addressed off)
            tre[wid][e][(fa | hi) ? 51 : myn] = (uint8_t)visiting;
            *(uint16_t*)&rg[wid][e][(cf & hi & (slot < NN)) ? 2 * slot : 102] =
                (uint16_t)(visiting | (myn << 8));
        }
        L &= ~bu;
        V &= ~visbit;
        M = Mn; visiting = nv;
        w = dn ? 0u : wn;   // done lanes idle harmlessly
        if (__ballot(!dn) == 0) break;
    }

    // ---------------- phase B: rings for this wave's 4 elements ----------------
    int*  otree = out;                                   // (B,51)
    int2* oridx = (int2*)(out + (size_t)BATCH * NN);     // (B,51) of int2

    // init + tree/ridx dump + interleaved 4-chain ancestor-mask doubling
    uint64_t MkE[EPW];
    int gE[EPW];
    #pragma unroll
    for (int e2 = 0; e2 < EPW; ++e2) {
        const int b = gbase + e2;
        const int f = (lane < NN) ? (int)tre[wid][e2][lane] : 0;
        MkE[e2] = ((uint64_t)1 << lane) | ((uint64_t)1 << f);
        gE[e2]  = f;
        if (lane < NN) {
            const uint32_t pv = *(const uint16_t*)&rg[wid][e2][2 * lane];
            otree[(size_t)b * NN + lane] = f;
            oridx[(size_t)b * NN + lane] = make_int2((int)(pv & 0xff), (int)(pv >> 8));
        }
    }
    #pragma unroll
    for (int j = 0; j < 6; ++j) {
        #pragma unroll
        for (int e2 = 0; e2 < EPW; ++e2) {
            const int ad = gE[e2] << 2;
            const int lo = __builtin_amdgcn_ds_bpermute(ad, (int)(uint32_t)MkE[e2]);
            const int hh = __builtin_amdgcn_ds_bpermute(ad, (int)(MkE[e2] >> 32));
            MkE[e2] |= ((uint64_t)(uint32_t)hh << 32) | (uint32_t)lo;
            if (j < 5) gE[e2] = __builtin_amdgcn_ds_bpermute(ad, gE[e2]);
        }
    }

    #pragma unroll 1
    for (int e2 = 0; e2 < EPW; ++e2) {
        const int b = gbase + e2;
        const uint64_t Mk = MkE[e2];
        const int dep = __builtin_popcountll(Mk) - 1;    // depth (distance to node 0)
        const int Mlo = (int)(uint32_t)Mk, Mhi = (int)(Mk >> 32);

        const uint32_t pv = (lane < NN) ? *(const uint16_t*)&rg[wid][e2][2 * lane] : 0;
        const int r0 = (int)(pv & 0xff), r1 = (int)(pv >> 8);  // ring_idx slots (lanes<16)

        // per-slot prep, parallel across lanes 0..15
        const int a0 = r0 << 2, a1 = r1 << 2;
        const uint64_t set0 = ((uint64_t)(uint32_t)__builtin_amdgcn_ds_bpermute(a0, Mhi) << 32)
                            |  (uint32_t)__builtin_amdgcn_ds_bpermute(a0, Mlo);
        const uint64_t set1 = ((uint64_t)(uint32_t)__builtin_amdgcn_ds_bpermute(a1, Mhi) << 32)
                            |  (uint32_t)__builtin_amdgcn_ds_bpermute(a1, Mlo);
        const int dm  = __builtin_popcountll(set0 & set1) - 1;  // LCA depth
        const int ds0 = __builtin_popcountll(set0) - 1;
        const int ds1 = __builtin_popcountll(set1) - 1;
        const int nact = __popcll(__ballot((lane < MAXR) && (r0 != 0)));

        const int s0lo = (int)(uint32_t)set0, s0hi = (int)(set0 >> 32);
        const int s1lo = (int)(uint32_t)set1, s1hi = (int)(set1 >> 32);
        int* orings = out + (size_t)BATCH * NN * 3 + (size_t)b * (MAXR * A);

        for (int i = 0; i < nact; ++i) {
            const uint64_t set0b = ((uint64_t)(uint32_t)__builtin_amdgcn_readlane(s0hi, i) << 32)
                                 |  (uint32_t)__builtin_amdgcn_readlane(s0lo, i);
            const uint64_t set1b = ((uint64_t)(uint32_t)__builtin_amdgcn_readlane(s1hi, i) << 32)
                                 |  (uint32_t)__builtin_amdgcn_readlane(s1lo, i);
            const int dmb  = __builtin_amdgcn_readlane(dm,  i);
            const int ds0b = __builtin_amdgcn_readlane(ds0, i);
            const int ds1b = __builtin_amdgcn_readlane(ds1, i);
            const int s0b  = __builtin_amdgcn_readlane(r0,  i);
            const int tb = ds1b - dmb, tub = tb + ds0b - dmb;

            const bool on1 = ((set1b >> lane) & 1) && (dep >= dmb);
            const bool on0 = ((set0b >> lane) & 1) && (dep >  dmb);
            int pos = on1 ? (ds1b - dep) : on0 ? (tb + 1 + ds0b - dep) : 63;
            pos = pos < 63 ? pos : 63;
            const int pm = __builtin_amdgcn_ds_permute(pos << 2, lane);  // node -> position
            const int rowval = (lane == tb + 1) ? s0b : (lane <= tub ? pm : 0);
            if (lane < A) orings[i * A + lane] = rowval - 1;
        }
        // tail fill: rows nact..15 are all -1 (contiguous, 8B aligned)
        {
            const int startw = nact * A;
            int2* p2 = (int2*)(orings + startw);
            const int n2 = (MAXR * A - startw) >> 1;
            for (int k = lane; k < n2; k += 64) p2[k] = make_int2(-1, -1);
        }
    }
}

extern "C" void kernel_launch(void* const* d_in, const int* in_sizes, int n_in,
                              void* d_out, int out_size, void* d_ws, size_t ws_size,
                              hipStream_t stream) {
    const int* edge = (const int*)d_in[0];
    int* out = (int*)d_out;
    hipLaunchKernelGGL(fused_kernel, dim3(BATCH / (EPW * WPB)), dim3(WPB * 64), 0, stream,
                       edge, out);
}

// Round 8
// 28.770 us; speedup vs baseline: 1.1416x; 1.1416x over previous
//
#include <hip/hip_runtime.h>
#include <stdint.h>

constexpr int BATCH = 16384;
constexpr int A     = 50;
constexpr int NN    = 51;   // A + 1
constexpr int MAXR  = 16;
constexpr int EPW   = 8;    // elements per wave (8 lanes per element) — round-6 optimum
constexpr int WPB   = 4;    // waves per block

// Fused kernel: phase A = octet-split prefetch-pipelined tree build (verbatim
// round 6); phase B = ring reconstruction with 8-way interleaved mask-doubling,
// hoisted slot prep, and paired ring-row emission. No __syncthreads.
__global__ __launch_bounds__(WPB * 64)
void fused_kernel(const int* __restrict__ edge, int* __restrict__ out)
{
    const int lane  = threadIdx.x & 63;
    const int wid   = threadIdx.x >> 6;
    const int gbase = (blockIdx.x * WPB + wid) * EPW;  // this wave's first element

    __shared__ uint32_t eds[WPB][EPW][NN];   // packed me[e][n+1][0..3]
    __shared__ uint8_t  tre[WPB][EPW][52];   // Tree bytes; slot 51 = trash
    __shared__ uint8_t  rg [WPB][EPW][104];  // ring_idx pairs; offset 102 = trash

    {   // zero tre + rg (wave-private slices)
        const uint4 z = make_uint4(0, 0, 0, 0);
        uint4* t16 = (uint4*)&tre[wid][0][0];           // 8*52/16 = 26
        if (lane < 26) t16[lane] = z;
        uint4* r16 = (uint4*)&rg[wid][0][0];            // 8*104/16 = 52
        if (lane < 52) r16[lane] = z;
    }
    {   // stage + pack this wave's edges: 8 elements x 50 int4, coalesced
        const int4* e4 = (const int4*)edge + (size_t)gbase * A;
        #pragma unroll
        for (int k = 0; k < 7; ++k) {
            const int gi = k * 64 + lane;
            if (gi < EPW * A) {
                const int4 v = e4[gi];
                const int el = gi / A, n = gi - A * el;
                eds[wid][el][n] = (uint32_t)(v.x + 1) | ((uint32_t)(v.y + 1) << 8)
                                | ((uint32_t)(v.z + 1) << 16) | ((uint32_t)(v.w + 1) << 24);
            }
        }
    }
    // (same-wave LDS RAW: hardware lgkmcnt ordering, no barrier needed)

    // ---------------- phase A: tree construction (round-6 verbatim) ----------------
    const int  e  = lane >> 3;    // element within wave
    const int  d8 = lane & 7;
    const int  d  = d8 & 3;       // edge index this lane mirrors
    const bool hi = d8 >= 4;      // hi half of octet: does the rg store

    uint64_t L = (((uint64_t)1 << NN) - 1) & ~(uint64_t)3;  // lnf: 0,1 found
    uint64_t V = (((uint64_t)1 << NN) - 1) & ~(uint64_t)1;  // nnv: 0 visited
    uint64_t M = 2;               // found & not visited = {1}
    int visiting = 1, nr = 0;
    uint32_t w = eds[wid][e][0];  // prefetched row of node 1

    #pragma unroll 1
    for (int it = 0; it < A; ++it) {
        const int n0 = w & 0xff, n1 = (w >> 8) & 0xff, n2 = (w >> 16) & 0xff, n3 = w >> 24;
        const uint64_t bu = ((uint64_t)1 << n0) | ((uint64_t)1 << n1)
                          | ((uint64_t)1 << n2) | ((uint64_t)1 << n3);
        const int myn = (w >> (8 * d)) & 0xff;
        const uint64_t bm = (uint64_t)1 << myn;
        // --- next-visit precompute + prefetch (overlaps bookkeeping) ---
        const uint64_t visbit = (uint64_t)1 << visiting;
        const uint64_t Mn = (M | (V & bu)) & ~visbit;   // next found&!visited set
        const bool dn = (Mn == 0);
        const uint64_t Msafe = dn ? (uint64_t)2 : Mn;
        const int nv = (int)__builtin_ctzll(Msafe);     // next visiting (dummy 1 if done)
        const uint32_t wn = eds[wid][e][nv - 1];        // prefetch next edge row
        // --- bookkeeping with OLD L,V ---
        const bool dup = ((d > 0) & (myn == n0)) | ((d > 1) & (myn == n1)) | ((d > 2) & (myn == n2));
        const bool fa  = ((L & bm) == 0) | dup;         // found at my edge's turn
        const bool cf  = fa & ((V & bm) != 0) & (myn != 0);   // cycle edge
        const bool cb  = cf & !hi;                      // ballot only low half
        const uint64_t Bc = __ballot(cb);
        const uint32_t qb = (uint32_t)(Bc >> (lane & 56)) & 0xfu;  // my octet's bits
        const int slot = nr + __builtin_popcount(qb & ((1u << d) - 1));
        nr += __builtin_popcount(qb);
        // lanes 0-3: Tree set-once; lanes 4-7: ring slot push (trash-addressed off)
        tre[wid][e][(fa | hi) ? 51 : myn] = (uint8_t)visiting;
        *(uint16_t*)&rg[wid][e][(cf & hi & (slot < NN)) ? 2 * slot : 102] =
            (uint16_t)(visiting | (myn << 8));
        L &= ~bu;
        V &= ~visbit;
        M = Mn; visiting = nv;
        w = dn ? 0u : wn;   // done lanes idle harmlessly
        if (__ballot(!dn) == 0) break;
    }

    // ---------------- phase B: rings, pipelined ----------------
    int*  otree = out;                                   // (B,51)
    int2* oridx = (int2*)(out + (size_t)BATCH * NN);     // (B,51) of int2

    // init: tree/ridx dump + doubling seeds (all static-unrolled; regs are free,
    // occupancy is grid-limited at 2 waves/SIMD)
    uint64_t MkE[EPW];
    int gE[EPW], r01E[EPW];
    #pragma unroll
    for (int e2 = 0; e2 < EPW; ++e2) {
        const int b = gbase + e2;
        const int f = (lane < NN) ? (int)tre[wid][e2][lane] : 0;
        const uint32_t pv = (lane < NN) ? *(const uint16_t*)&rg[wid][e2][2 * lane] : 0;
        MkE[e2] = ((uint64_t)1 << lane) | ((uint64_t)1 << f);
        gE[e2]  = f;
        r01E[e2] = (int)pv;                              // slot lane: r0 | r1<<8
        if (lane < NN) {
            otree[(size_t)b * NN + lane] = f;
            oridx[(size_t)b * NN + lane] = make_int2((int)(pv & 0xff), (int)(pv >> 8));
        }
    }
    // 8-way interleaved ancestor-mask doubling: 24 independent bpermutes per step
    #pragma unroll
    for (int j = 0; j < 6; ++j) {
        #pragma unroll
        for (int e2 = 0; e2 < EPW; ++e2) {
            const int ad = gE[e2] << 2;
            const int lo = __builtin_amdgcn_ds_bpermute(ad, (int)(uint32_t)MkE[e2]);
            const int hh = __builtin_amdgcn_ds_bpermute(ad, (int)(MkE[e2] >> 32));
            MkE[e2] |= ((uint64_t)(uint32_t)hh << 32) | (uint32_t)lo;
            if (j < 5) gE[e2] = __builtin_amdgcn_ds_bpermute(ad, gE[e2]);
        }
    }
    // hoisted slot prep for all 8 elements (32 independent bpermutes in flight)
    int depE[EPW], nactE[EPW], packE[EPW];
    int s0loE[EPW], s0hiE[EPW], s1loE[EPW], s1hiE[EPW];
    #pragma unroll
    for (int e2 = 0; e2 < EPW; ++e2) {
        const uint64_t Mk = MkE[e2];
        depE[e2] = __builtin_popcountll(Mk) - 1;
        const int Mlo = (int)(uint32_t)Mk, Mhi = (int)(Mk >> 32);
        const int r0 = r01E[e2] & 0xff, r1 = (r01E[e2] >> 8) & 0xff;
        const int a0 = r0 << 2, a1 = r1 << 2;
        const uint64_t set0 = ((uint64_t)(uint32_t)__builtin_amdgcn_ds_bpermute(a0, Mhi) << 32)
                            |  (uint32_t)__builtin_amdgcn_ds_bpermute(a0, Mlo);
        const uint64_t set1 = ((uint64_t)(uint32_t)__builtin_amdgcn_ds_bpermute(a1, Mhi) << 32)
                            |  (uint32_t)__builtin_amdgcn_ds_bpermute(a1, Mlo);
        const int dm  = __builtin_popcountll(set0 & set1) - 1;  // LCA depth
        const int ds0 = __builtin_popcountll(set0) - 1;
        const int ds1 = __builtin_popcountll(set1) - 1;
        s0loE[e2] = (int)(uint32_t)set0;  s0hiE[e2] = (int)(set0 >> 32);
        s1loE[e2] = (int)(uint32_t)set1;  s1hiE[e2] = (int)(set1 >> 32);
        packE[e2] = dm | (ds0 << 8) | (ds1 << 16);               // all < 64
        nactE[e2] = __popcll(__ballot((lane < MAXR) && (r0 != 0)));
    }

    // row emission, 2 rows per iteration (independent ds_permutes overlap)
    #pragma unroll
    for (int e2 = 0; e2 < EPW; ++e2) {
        const int b = gbase + e2;
        int* orings = out + (size_t)BATCH * NN * 3 + (size_t)b * (MAXR * A);
        const int nact = nactE[e2];
        const int dep  = depE[e2];

        int i = 0;
        for (; i + 1 < nact; i += 2) {
            // ---- row i ----
            const uint64_t s0a = ((uint64_t)(uint32_t)__builtin_amdgcn_readlane(s0hiE[e2], i) << 32)
                               |  (uint32_t)__builtin_amdgcn_readlane(s0loE[e2], i);
            const uint64_t s1a = ((uint64_t)(uint32_t)__builtin_amdgcn_readlane(s1hiE[e2], i) << 32)
                               |  (uint32_t)__builtin_amdgcn_readlane(s1loE[e2], i);
            const int pka = __builtin_amdgcn_readlane(packE[e2], i);
            const int s0va = __builtin_amdgcn_readlane(r01E[e2], i) & 0xff;
            const int dma = pka & 0xff, ds0a = (pka >> 8) & 0xff, ds1a = (pka >> 16) & 0xff;
            const int ta = ds1a - dma, tua = ta + ds0a - dma;
            const bool on1a = ((s1a >> lane) & 1) && (dep >= dma);
            const bool on0a = ((s0a >> lane) & 1) && (dep >  dma);
            int posa = on1a ? (ds1a - dep) : on0a ? (ta + 1 + ds0a - dep) : 63;
            posa = posa < 63 ? posa : 63;
            // ---- row i+1 ----
            const uint64_t s0b = ((uint64_t)(uint32_t)__builtin_amdgcn_readlane(s0hiE[e2], i + 1) << 32)
                               |  (uint32_t)__builtin_amdgcn_readlane(s0loE[e2], i + 1);
            const uint64_t s1b = ((uint64_t)(uint32_t)__builtin_amdgcn_readlane(s1hiE[e2], i + 1) << 32)
                               |  (uint32_t)__builtin_amdgcn_readlane(s1loE[e2], i + 1);
            const int pkb = __builtin_amdgcn_readlane(packE[e2], i + 1);
            const int s0vb = __builtin_amdgcn_readlane(r01E[e2], i + 1) & 0xff;
            const int dmb = pkb & 0xff, ds0b = (pkb >> 8) & 0xff, ds1b = (pkb >> 16) & 0xff;
            const int tb = ds1b - dmb, tub = tb + ds0b - dmb;
            const bool on1b = ((s1b >> lane) & 1) && (dep >= dmb);
            const bool on0b = ((s0b >> lane) & 1) && (dep >  dmb);
            int posb = on1b ? (ds1b - dep) : on0b ? (tb + 1 + ds0b - dep) : 63;
            posb = posb < 63 ? posb : 63;
            // two independent scatters issue back-to-back
            const int pma = __builtin_amdgcn_ds_permute(posa << 2, lane);
            const int pmb = __builtin_amdgcn_ds_permute(posb << 2, lane);
            const int rva = (lane == ta + 1) ? s0va : (lane <= tua ? pma : 0);
            const int rvb = (lane == tb + 1) ? s0vb : (lane <= tub ? pmb : 0);
            if (lane < A) {
                orings[i * A + lane]       = rva - 1;
                orings[(i + 1) * A + lane] = rvb - 1;
            }
        }
        if (i < nact) {  // odd tail row
            const uint64_t s0a = ((uint64_t)(uint32_t)__builtin_amdgcn_readlane(s0hiE[e2], i) << 32)
                               |  (uint32_t)__builtin_amdgcn_readlane(s0loE[e2], i);
            const uint64_t s1a = ((uint64_t)(uint32_t)__builtin_amdgcn_readlane(s1hiE[e2], i) << 32)
                               |  (uint32_t)__builtin_amdgcn_readlane(s1loE[e2], i);
            const int pka = __builtin_amdgcn_readlane(packE[e2], i);
            const int s0va = __builtin_amdgcn_readlane(r01E[e2], i) & 0xff;
            const int dma = pka & 0xff, ds0a = (pka >> 8) & 0xff, ds1a = (pka >> 16) & 0xff;
            const int ta = ds1a - dma, tua = ta + ds0a - dma;
            const bool on1a = ((s1a >> lane) & 1) && (dep >= dma);
            const bool on0a = ((s0a >> lane) & 1) && (dep >  dma);
            int posa = on1a ? (ds1a - dep) : on0a ? (ta + 1 + ds0a - dep) : 63;
            posa = posa < 63 ? posa : 63;
            const int pma = __builtin_amdgcn_ds_permute(posa << 2, lane);
            const int rva = (lane == ta + 1) ? s0va : (lane <= tua ? pma : 0);
            if (lane < A) orings[i * A + lane] = rva - 1;
        }
        // tail fill: rows nact..15 are all -1 (contiguous, 8B aligned)
        const int startw = nact * A;
        int2* p2 = (int2*)(orings + startw);
        const int n2 = (MAXR * A - startw) >> 1;
        for (int k = lane; k < n2; k += 64) p2[k] = make_int2(-1, -1);
    }
}

extern "C" void kernel_launch(void* const* d_in, const int* in_sizes, int n_in,
                              void* d_out, int out_size, void* d_ws, size_t ws_size,
                              hipStream_t stream) {
    const int* edge = (const int*)d_in[0];
    int* out = (int*)d_out;
    hipLaunchKernelGGL(fused_kernel, dim3(BATCH / (EPW * WPB)), dim3(WPB * 64), 0, stream,
                       edge, out);
}